// Round 18
// baseline (222.503 us; speedup 1.0000x reference)
//
#include <hip/hip_runtime.h>

#define HIDDEN 2048
#define S_LEN  2048
#define NH     32
#define NKV    8
#define HD     128
#define QKVN   6144   // 4096 q + 1024 k + 1024 v
#define OD     4096   // NH*HD

typedef float  f32x4   __attribute__((ext_vector_type(4)));
typedef float  f32x16  __attribute__((ext_vector_type(16)));
typedef __bf16 bf16x8  __attribute__((ext_vector_type(8)));
typedef __bf16 bf16x4  __attribute__((ext_vector_type(4)));
typedef unsigned int u32;

static __device__ __forceinline__ f32x4 mfma16(bf16x8 a, bf16x8 b, f32x4 c) {
  return __builtin_amdgcn_mfma_f32_16x16x32_bf16(a, b, c, 0, 0, 0);
}
static __device__ __forceinline__ f32x16 mfma32(bf16x8 a, bf16x8 b, f32x16 c) {
  return __builtin_amdgcn_mfma_f32_32x32x16_bf16(a, b, c, 0, 0, 0);
}
static __device__ __forceinline__ void gload_lds16(const void* g, void* l) {
  __builtin_amdgcn_global_load_lds(
      (__attribute__((address_space(1))) void*)(g),
      (__attribute__((address_space(3))) void*)(l), 16, 0, 0);
}
static __device__ __forceinline__ u32 pk_bf16(float lo, float hi) {
  u32 r;
  asm("v_cvt_pk_bf16_f32 %0, %1, %2" : "=v"(r) : "v"(lo), "v"(hi));
  return r;
}

// ---------- fp32 -> bf16 elementwise ----------
__global__ __launch_bounds__(256) void k_cvt(const float* __restrict__ in,
                                             __bf16* __restrict__ out, int n) {
  int i = (blockIdx.x * 256 + threadIdx.x) * 4;
  if (i >= n) return;
  float4 v = *reinterpret_cast<const float4*>(in + i);
  bf16x4 o = {(__bf16)v.x, (__bf16)v.y, (__bf16)v.z, (__bf16)v.w};
  *reinterpret_cast<bf16x4*>(out + i) = o;
}

// ---------- fused wq/wk/wv transpose+convert into wqkvT (z selects matrix) ----------
__global__ __launch_bounds__(256) void k_transpose_qkv(const float* __restrict__ wq,
                                                       const float* __restrict__ wk,
                                                       const float* __restrict__ wv,
                                                       __bf16* __restrict__ dst) {
  __shared__ float tile[32][33];
  const int z = blockIdx.z;
  const float* src = (z == 0) ? wq : (z == 1 ? wk : wv);
  const int Nsrc = (z == 0) ? 4096 : 1024;
  const int coff = (z == 0) ? 0 : (z == 1 ? 4096 : 5120);
  int tx = threadIdx.x & 31, ty = threadIdx.x >> 5;
  int n0 = blockIdx.x * 32, k0 = blockIdx.y * 32;
  if (n0 >= Nsrc) return;
#pragma unroll
  for (int r = 0; r < 4; r++) {
    int k = ty + r * 8;
    tile[k][tx] = src[(size_t)(k0 + k) * Nsrc + n0 + tx];
  }
  __syncthreads();
#pragma unroll
  for (int r = 0; r < 4; r++) {
    int n = ty + r * 8;
    dst[(size_t)(coff + n0 + n) * HIDDEN + k0 + tx] = (__bf16)tile[tx][n];
  }
}

// ---------- transpose + convert: src (K x N) f32 -> dst (N x K) bf16 ----------
__global__ __launch_bounds__(256) void k_transpose_cvt(const float* __restrict__ src,
                                                       __bf16* __restrict__ dst,
                                                       int K, int N) {
  __shared__ float tile[32][33];
  int tx = threadIdx.x & 31, ty = threadIdx.x >> 5;
  int n0 = blockIdx.x * 32, k0 = blockIdx.y * 32;
#pragma unroll
  for (int r = 0; r < 4; r++) {
    int k = ty + r * 8;
    tile[k][tx] = src[(size_t)(k0 + k) * N + n0 + tx];
  }
  __syncthreads();
#pragma unroll
  for (int r = 0; r < 4; r++) {
    int n = ty + r * 8;
    dst[(size_t)(n0 + n) * K + k0 + tx] = (__bf16)tile[tx][n];
  }
}

__global__ void k_bias_concat(const float* __restrict__ bq, const float* __restrict__ bk,
                              const float* __restrict__ bv, float* __restrict__ out) {
  int i = blockIdx.x * 256 + threadIdx.x;
  if (i >= QKVN) return;
  out[i] = (i < 4096) ? bq[i] : (i < 5120 ? bk[i - 4096] : bv[i - 5120]);
}

// ---------- V transpose: qkv (S x QKVN) v-cols -> vt (NKV x HD x S) ----------
__global__ __launch_bounds__(256) void k_vtrans(const __bf16* __restrict__ qkv,
                                                __bf16* __restrict__ vt) {
  __shared__ __bf16 tile[32][33];
  int tx = threadIdx.x & 31, ty = threadIdx.x >> 5;
  int s0 = blockIdx.x * 32, d0 = blockIdx.y * 32, kv = blockIdx.z;
#pragma unroll
  for (int r = 0; r < 4; r++) {
    int s = ty + r * 8;
    tile[s][tx] = qkv[(size_t)(s0 + s) * QKVN + 5120 + kv * HD + d0 + tx];
  }
  __syncthreads();
#pragma unroll
  for (int r = 0; r < 4; r++) {
    int d = ty + r * 8;
    vt[(size_t)(kv * HD + d0 + d) * S_LEN + s0 + tx] = tile[tx][d];
  }
}

// ---------- 128x192 BK=64 GEMM, 2 phases/K-tile, counted vmcnt (T2+T4+T5) ----------
// C = (A@BT^T + bias)*colscale. 256 threads = 4 waves (1M x 4N); per-wave
// C = 128x48 (8x3 frags 16x16x32), acc[8][3] ~ 96 VGPR.
// LDS 80 KiB -> 2 blocks/CU = full coverage at grid 512. XOR swizzle
// slot^=((row>>1)&3), pre-swizzled source (rule #21). Uniform 5 staging
// loads/thread per K-half -> counted vmcnt(5) publishes (wait BEFORE barrier).
__global__ __launch_bounds__(256, 2) void k_gemm8(const __bf16* __restrict__ A,
                                                  const __bf16* __restrict__ BT,
                                                  const float* __restrict__ bias,
                                                  __bf16* __restrict__ C,
                                                  int M, int N, int K,
                                                  float oscale, int scale_cols) {
  __shared__ __bf16 Al[2][2][4096];   // [dbuf][khalf][128 rows x 32 k]
  __shared__ __bf16 Bl[2][2][6144];   // [dbuf][khalf][192 rows x 32 k]
  const int tid = threadIdx.x, lane = tid & 63, w = tid >> 6;
  const int l15 = lane & 15, lhi = lane >> 4;
  const int sw = ((blockIdx.x & 7) << 6) + (blockIdx.x >> 3);  // XCD-chunked
  const int mt = sw & 15, nt = sw >> 4;
  const int m0 = mt * 128, n0 = nt * 192;
  const int NKT = K >> 6;
  const __bf16* Ab = A + (size_t)m0 * K;
  const __bf16* Bb = BT + (size_t)n0 * K;

  f32x4 acc[8][3];
#pragma unroll
  for (int i = 0; i < 8; i++)
#pragma unroll
    for (int j = 0; j < 3; j++)
#pragma unroll
      for (int e = 0; e < 4; e++) acc[i][j][e] = 0.f;

#define SGH(buf, kh, ktile)                                                       \
  do {                                                                            \
    _Pragma("unroll") for (int it = 0; it < 2; ++it) {                            \
      int c = it * 256 + tid;                                                     \
      int row = c >> 2, slot = c & 3;                                             \
      int scol = ((slot * 16) ^ (((row >> 1) & 3) << 4)) >> 1;                    \
      gload_lds16(Ab + (size_t)row * K + (ktile) * 64 + (kh) * 32 + scol,         \
                  &Al[buf][kh][c * 8]);                                           \
    }                                                                             \
    _Pragma("unroll") for (int it = 0; it < 3; ++it) {                            \
      int c = it * 256 + tid;                                                     \
      int row = c >> 2, slot = c & 3;                                             \
      int scol = ((slot * 16) ^ (((row >> 1) & 3) << 4)) >> 1;                    \
      gload_lds16(Bb + (size_t)row * K + (ktile) * 64 + (kh) * 32 + scol,         \
                  &Bl[buf][kh][c * 8]);                                           \
    }                                                                             \
  } while (0)

#define RD_AB(cb, kk)                                                             \
  do {                                                                            \
    _Pragma("unroll") for (int i = 0; i < 8; ++i) {                               \
      int row = i * 16 + l15;                                                     \
      af[i] = *(const bf16x8*)(&Al[cb][kk][row * 32 +                             \
                (((lhi * 16) ^ (((row >> 1) & 3) << 4)) >> 1)]);                  \
    }                                                                             \
    _Pragma("unroll") for (int j = 0; j < 3; ++j) {                               \
      int row = w * 48 + j * 16 + l15;                                            \
      bfr[j] = *(const bf16x8*)(&Bl[cb][kk][row * 32 +                            \
                (((lhi * 16) ^ (((row >> 1) & 3) << 4)) >> 1)]);                  \
    }                                                                             \
  } while (0)

#define MFMA24X                                                                   \
  do {                                                                            \
    __builtin_amdgcn_s_setprio(1);                                                \
    _Pragma("unroll") for (int i = 0; i < 8; ++i) {                               \
      _Pragma("unroll") for (int j = 0; j < 3; ++j) {                             \
        acc[i][j] = mfma16(af[i], bfr[j], acc[i][j]);                             \
      }                                                                           \
    }                                                                             \
    __builtin_amdgcn_s_setprio(0);                                                \
  } while (0)

  SGH(0, 0, 0);
  SGH(0, 1, 0);
  asm volatile("s_waitcnt vmcnt(5)" ::: "memory");
  __builtin_amdgcn_s_barrier();
  __builtin_amdgcn_sched_barrier(0);

  for (int kt = 0; kt < NKT; ++kt) {
    const int cb = kt & 1, pb = cb ^ 1;
    const bool pf = (kt + 1 < NKT);
    bf16x8 af[8], bfr[3];

    RD_AB(cb, 0);
    if (pf) SGH(pb, 0, kt + 1);
    __builtin_amdgcn_s_barrier();
    asm volatile("s_waitcnt lgkmcnt(0)" ::: "memory");
    MFMA24X;
    if (pf) {
      asm volatile("s_waitcnt vmcnt(5)" ::: "memory");
    } else {
      asm volatile("s_waitcnt vmcnt(0)" ::: "memory");
    }
    __builtin_amdgcn_s_barrier();
    __builtin_amdgcn_sched_barrier(0);

    RD_AB(cb, 1);
    if (pf) SGH(pb, 1, kt + 1);
    __builtin_amdgcn_s_barrier();
    asm volatile("s_waitcnt lgkmcnt(0)" ::: "memory");
    MFMA24X;
    if (pf) {
      asm volatile("s_waitcnt vmcnt(5)" ::: "memory");
    }
    __builtin_amdgcn_s_barrier();
    __builtin_amdgcn_sched_barrier(0);
  }
#undef SGH
#undef RD_AB
#undef MFMA24X

#pragma unroll
  for (int j = 0; j < 3; j++) {
    int col = n0 + w * 48 + j * 16 + l15;
    float bv = bias[col];
    float sc = (col < scale_cols) ? oscale : 1.0f;
#pragma unroll
    for (int i = 0; i < 8; i++) {
      int r0 = m0 + i * 16 + lhi * 4;
#pragma unroll
      for (int rr = 0; rr < 4; rr++) {
        C[(size_t)(r0 + rr) * N + col] = (__bf16)((acc[i][j][rr] + bv) * sc);
      }
    }
  }
}

// ---------- split-K O-GEMM partial, 2-phase counted-vmcnt dbuf ----------
__global__ __launch_bounds__(256, 2) void k_gemm_part(const __bf16* __restrict__ A,
                                                      const __bf16* __restrict__ BT,
                                                      float* __restrict__ Cpart,
                                                      int M, int N, int K, int KC) {
  __shared__ __bf16 Al[2][2][4096];   // [dbuf][khalf][128 rows x 32 k]
  __shared__ __bf16 Bl[2][2][4096];
  const int tid = threadIdx.x, lane = tid & 63, w = tid >> 6;
  const int l15 = lane & 15, lhi = lane >> 4;
  const int bid = blockIdx.x;
  const int z = bid >> 8, rem = bid & 255;
  const int sw = ((rem & 7) << 5) + (rem >> 3);  // XCD-chunked, bijective on 256
  const int mt = sw & 15, nt = sw >> 4;
  const int m0 = mt * 128, n0 = nt * 128;
  const int NKT = KC >> 6;
  const __bf16* Ab = A + (size_t)m0 * K + (size_t)z * KC;
  const __bf16* Bb = BT + (size_t)n0 * K + (size_t)z * KC;

  f32x4 acc[8][2];
#pragma unroll
  for (int i = 0; i < 8; i++)
#pragma unroll
    for (int j = 0; j < 2; j++)
#pragma unroll
      for (int e = 0; e < 4; e++) acc[i][j][e] = 0.f;

#define SGH2(buf, kh, ktile)                                                      \
  do {                                                                            \
    _Pragma("unroll") for (int it = 0; it < 2; ++it) {                            \
      int c = it * 256 + tid;                                                     \
      int row = c >> 2, slot = c & 3;                                             \
      int scol = ((slot * 16) ^ (((row >> 1) & 3) << 4)) >> 1;                    \
      gload_lds16(Ab + (size_t)row * K + (ktile) * 64 + (kh) * 32 + scol,         \
                  &Al[buf][kh][c * 8]);                                           \
    }                                                                             \
    _Pragma("unroll") for (int it = 0; it < 2; ++it) {                            \
      int c = it * 256 + tid;                                                     \
      int row = c >> 2, slot = c & 3;                                             \
      int scol = ((slot * 16) ^ (((row >> 1) & 3) << 4)) >> 1;                    \
      gload_lds16(Bb + (size_t)row * K + (ktile) * 64 + (kh) * 32 + scol,         \
                  &Bl[buf][kh][c * 8]);                                           \
    }                                                                             \
  } while (0)

#define RD_AB2(cb, kk)                                                            \
  do {                                                                            \
    _Pragma("unroll") for (int i = 0; i < 8; ++i) {                               \
      int row = i * 16 + l15;                                                     \
      af[i] = *(const bf16x8*)(&Al[cb][kk][row * 32 +                             \
                (((lhi * 16) ^ (((row >> 1) & 3) << 4)) >> 1)]);                  \
    }                                                                             \
    _Pragma("unroll") for (int j = 0; j < 2; ++j) {                               \
      int row = w * 32 + j * 16 + l15;                                            \
      bfr[j] = *(const bf16x8*)(&Bl[cb][kk][row * 32 +                            \
                (((lhi * 16) ^ (((row >> 1) & 3) << 4)) >> 1)]);                  \
    }                                                                             \
  } while (0)

#define MFMA16X                                                                   \
  do {                                                                            \
    __builtin_amdgcn_s_setprio(1);                                                \
    _Pragma("unroll") for (int i = 0; i < 8; ++i) {                               \
      _Pragma("unroll") for (int j = 0; j < 2; ++j) {                             \
        acc[i][j] = mfma16(af[i], bfr[j], acc[i][j]);                             \
      }                                                                           \
    }                                                                             \
    __builtin_amdgcn_s_setprio(0);                                                \
  } while (0)

  SGH2(0, 0, 0);
  SGH2(0, 1, 0);
  asm volatile("s_waitcnt vmcnt(4)" ::: "memory");
  __builtin_amdgcn_s_barrier();
  __builtin_amdgcn_sched_barrier(0);

  for (int kt = 0; kt < NKT; ++kt) {
    const int cb = kt & 1, pb = cb ^ 1;
    const bool pf = (kt + 1 < NKT);
    bf16x8 af[8], bfr[2];

    RD_AB2(cb, 0);
    if (pf) SGH2(pb, 0, kt + 1);
    __builtin_amdgcn_s_barrier();
    asm volatile("s_waitcnt lgkmcnt(0)" ::: "memory");
    MFMA16X;
    if (pf) {
      asm volatile("s_waitcnt vmcnt(4)" ::: "memory");
    } else {
      asm volatile("s_waitcnt vmcnt(0)" ::: "memory");
    }
    __builtin_amdgcn_s_barrier();
    __builtin_amdgcn_sched_barrier(0);

    RD_AB2(cb, 1);
    if (pf) SGH2(pb, 1, kt + 1);
    __builtin_amdgcn_s_barrier();
    asm volatile("s_waitcnt lgkmcnt(0)" ::: "memory");
    MFMA16X;
    if (pf) {
      asm volatile("s_waitcnt vmcnt(4)" ::: "memory");
    }
    __builtin_amdgcn_s_barrier();
    __builtin_amdgcn_sched_barrier(0);
  }
#undef SGH2
#undef RD_AB2
#undef MFMA16X

  float* C = Cpart + (size_t)z * M * N;
#pragma unroll
  for (int j = 0; j < 2; j++) {
    int col = n0 + w * 32 + j * 16 + l15;
#pragma unroll
    for (int i = 0; i < 8; i++) {
      int r0 = m0 + i * 16 + lhi * 4;
#pragma unroll
      for (int rr = 0; rr < 4; rr++) {
        C[(size_t)(r0 + rr) * N + col] = acc[i][j][rr];
      }
    }
  }
}

// ---------- combine split-K partials + bias -> f32 out ----------
__global__ __launch_bounds__(256) void k_ocombine(const float* __restrict__ a,
                                                  const float* __restrict__ b,
                                                  const float* __restrict__ bias,
                                                  float* __restrict__ out) {
  int i = (blockIdx.x * 256 + threadIdx.x) * 4;
  f32x4 va = *(const f32x4*)(a + i);
  f32x4 vb = *(const f32x4*)(b + i);
  f32x4 vbias = *(const f32x4*)(bias + (i & (HIDDEN - 1)));
  f32x4 r = va + vb + vbias;
  *(f32x4*)(out + i) = r;
}

// ---------- causal GQA flash attention (r12 decomposition + exp2 softmax) ----------
// 512 blocks, 256 threads; ids i and i+256 get tiles t and 15-t. 4 waves x 32
// q-rows. Double-buffered K/V (64 KiB), coalesced staging, pre-swizzled source
// (rule #21). Q is pre-scaled by (1/sqrt(d))*log2(e) in the QKV GEMM epilogue,
// so softmax uses exp2 directly (v_exp_f32 IS 2^x: saves the ln2-mul per exp)
// and the row-sum is a depth-5 tree (was a 32-deep serial add chain).
// S^T = mfma(K,Q) so q = lane&31; P in registers via cvt_pk + permlane32_swap;
// O^T = mfma(V^T, P). LDS swizzles:
//   Kl[key][d]: byte = key*256 + ((2d) ^ ((key&15)<<4))   (reads 2-way, free)
//   Vl[d][k]:   byte = d*128  + ((2k) ^ ((d&7)<<4))       (reads 4-way, 1.58x)
__global__ __launch_bounds__(256, 2) void k_attn(const __bf16* __restrict__ qkv,
                                                 const __bf16* __restrict__ vt,
                                                 __bf16* __restrict__ o) {
  __shared__ __bf16 Kl[2][8192];
  __shared__ __bf16 Vl[2][8192];
  const int tid = threadIdx.x, lane = tid & 63, w = tid >> 6;
  const int l31 = lane & 31, h = lane >> 5;

  // block-id pairing: ids i and i+256 get tiles t and 15-t (uniform CU load)
  const int id = blockIdx.x;
  int tile, head;
  if (id < 256) { head = id >> 4; tile = id & 15; }
  else          { head = 16 + ((id - 256) >> 4); tile = 15 - (id & 15); }
  const int kvh = head >> 2;
  const int qbase = tile * 128 + w * 32;
  const int qg = qbase + l31;          // this lane's q row
  const int kdiag = (qbase + 31) >> 6; // last (partial) key tile for this wave
  const int nkt = 2 * tile + 2;

  // Q fragments (pre-scaled by log2e/sqrt(d) in QKV GEMM epilogue): B-frag col=q
  bf16x8 qf[8];
  {
    const __bf16* qrow = qkv + (size_t)qg * QKVN + head * HD;
#pragma unroll
    for (int dk = 0; dk < 8; dk++) qf[dk] = *(const bf16x8*)(qrow + dk * 16 + h * 8);
  }

  f32x16 acc[4];  // O^T: col=q=lane&31, row=d (reg-mapped), dt*32 block
#pragma unroll
  for (int dt = 0; dt < 4; dt++)
#pragma unroll
    for (int r = 0; r < 16; r++) acc[dt][r] = 0.f;
  float m = -INFINITY, lsum = 0.f;

#define STAGE(buf, ktile)                                                           \
  do {                                                                              \
    const int kk0 = (ktile) * 64;                                                   \
    _Pragma("unroll") for (int it = 0; it < 4; it++) {                              \
      int c = it * 256 + tid;                                                       \
      int key = c >> 4, slot = c & 15;                                              \
      int scol = ((slot * 16) ^ ((key & 15) << 4)) >> 1;                            \
      gload_lds16(qkv + (size_t)(kk0 + key) * QKVN + 4096 + kvh * HD + scol,        \
                  &Kl[buf][c * 8]);                                                 \
    }                                                                               \
    _Pragma("unroll") for (int it = 0; it < 4; it++) {                              \
      int c = it * 256 + tid;                                                       \
      int d = c >> 3, slot = c & 7;                                                 \
      int scol = ((slot * 16) ^ ((d & 7) << 4)) >> 1;                               \
      gload_lds16(vt + (size_t)(kvh * HD + d) * S_LEN + kk0 + scol,                 \
                  &Vl[buf][c * 8]);                                                 \
    }                                                                               \
  } while (0)

  STAGE(0, 0);
  __syncthreads();

  for (int kt = 0; kt < nkt; kt++) {
    const int cur = kt & 1;
    if (kt + 1 < nkt) STAGE(cur ^ 1, kt + 1);  // in flight during compute

    if (kt <= kdiag) {
      const char* Kb = (const char*)&Kl[cur][0];
      const char* Vb = (const char*)&Vl[cur][0];
      const int k0 = kt * 64;
      // ---- QK^T: S^T[key][q], two 32-key blocks ----
      f32x16 sacc[2];
#pragma unroll
      for (int b = 0; b < 2; b++)
#pragma unroll
        for (int r = 0; r < 16; r++) sacc[b][r] = 0.f;
      __builtin_amdgcn_s_setprio(1);
#pragma unroll
      for (int dk = 0; dk < 8; dk++) {
        const int sA = ((2 * dk + h) ^ (l31 & 15)) * 16;
        bf16x8 kf0 = *(const bf16x8*)(Kb + l31 * 256 + sA);
        bf16x8 kf1 = *(const bf16x8*)(Kb + (32 + l31) * 256 + sA);
        sacc[0] = mfma32(kf0, qf[dk], sacc[0]);
        sacc[1] = mfma32(kf1, qf[dk], sacc[1]);
      }
      __builtin_amdgcn_s_setprio(0);
      // ---- softmax in log2 domain (lane-local; q = lane&31) ----
      float p[32];
#pragma unroll
      for (int b = 0; b < 2; b++)
#pragma unroll
        for (int r = 0; r < 16; r++) p[b * 16 + r] = sacc[b][r];
      if (kt == kdiag) {  // mask only on the diagonal tile
#pragma unroll
        for (int b = 0; b < 2; b++)
#pragma unroll
          for (int r = 0; r < 16; r++) {
            int keyg = k0 + b * 32 + (r & 3) + 8 * (r >> 2) + 4 * h;
            if (keyg > qg) p[b * 16 + r] = -INFINITY;
          }
      }
      // pairwise max tree (depth 5)
      float t16[16], t8[8], t4[4];
#pragma unroll
      for (int i = 0; i < 16; i++) t16[i] = fmaxf(p[2 * i], p[2 * i + 1]);
#pragma unroll
      for (int i = 0; i < 8; i++) t8[i] = fmaxf(t16[2 * i], t16[2 * i + 1]);
#pragma unroll
      for (int i = 0; i < 4; i++) t4[i] = fmaxf(t8[2 * i], t8[2 * i + 1]);
      float pm = fmaxf(fmaxf(t4[0], t4[1]), fmaxf(t4[2], t4[3]));
      pm = fmaxf(pm, __shfl_xor(pm, 32));
      if (__any(pm - m > 8.f)) {  // defer-max (T13), log2 units
        float mn = fmaxf(m, pm);
        float corr = exp2f(m - mn);
        m = mn;
        lsum *= corr;
#pragma unroll
        for (int dt = 0; dt < 4; dt++)
#pragma unroll
          for (int r = 0; r < 16; r++) acc[dt][r] *= corr;
      }
      // p = 2^(s - m); row-sum as depth-5 tree (not a 32-deep serial chain)
#pragma unroll
      for (int i = 0; i < 32; i++) p[i] = exp2f(p[i] - m);
      float u16[16], u8[8], u4[4];
#pragma unroll
      for (int i = 0; i < 16; i++) u16[i] = p[2 * i] + p[2 * i + 1];
#pragma unroll
      for (int i = 0; i < 8; i++) u8[i] = u16[2 * i] + u16[2 * i + 1];
#pragma unroll
      for (int i = 0; i < 4; i++) u4[i] = u8[2 * i] + u8[2 * i + 1];
      lsum += (u4[0] + u4[1]) + (u4[2] + u4[3]);
      // ---- PV: O^T += V^T * P, P-frags built in-register ----
      // permlane32_swap(W0,W2): W0 -> {lo:W0@h0, hi:W2@h0}, W2 -> {lo:W0@h1, hi:W2@h1}.
#pragma unroll
      for (int ks2 = 0; ks2 < 4; ks2++) {
        const int o8 = (ks2 >> 1) * 16 + (ks2 & 1) * 8;
        u32 W0 = pk_bf16(p[o8 + 0], p[o8 + 1]);
        u32 W1 = pk_bf16(p[o8 + 2], p[o8 + 3]);
        u32 W2 = pk_bf16(p[o8 + 4], p[o8 + 5]);
        u32 W3 = pk_bf16(p[o8 + 6], p[o8 + 7]);
        asm("v_permlane32_swap_b32 %0, %1" : "+v"(W0), "+v"(W2));
        asm("v_permlane32_swap_b32 %0, %1" : "+v"(W1), "+v"(W3));
        union { u32 wd[4]; bf16x8 v; } pu;
        pu.wd[0] = W0; pu.wd[1] = W1; pu.wd[2] = W2; pu.wd[3] = W3;
        __builtin_amdgcn_s_setprio(1);
#pragma unroll
        for (int dt = 0; dt < 4; dt++) {
          const int dr = dt * 32 + l31;
          const int sV = ((2 * ks2 + h) ^ (dr & 7)) * 16;
          bf16x8 vf = *(const bf16x8*)(Vb + dr * 128 + sV);
          acc[dt] = mfma32(vf, pu.v, acc[dt]);
        }
        __builtin_amdgcn_s_setprio(0);
      }
    }
    __syncthreads();  // drains vmcnt: next tile landed; buffers safe to swap
  }
#undef STAGE

  // ---- finalize: combine the two key-halves, normalize, store ----
  lsum += __shfl_xor(lsum, 32);
  const float inv = 1.f / lsum;
  __bf16* orow = o + (size_t)qg * OD + head * HD;
#pragma unroll
  for (int dt = 0; dt < 4; dt++)
#pragma unroll
    for (int rq = 0; rq < 4; rq++) {  // reg quads -> 4 consecutive d
      int d = dt * 32 + 8 * rq + 4 * h;
      bf16x4 ov = {(__bf16)(acc[dt][rq * 4 + 0] * inv), (__bf16)(acc[dt][rq * 4 + 1] * inv),
                   (__bf16)(acc[dt][rq * 4 + 2] * inv), (__bf16)(acc[dt][rq * 4 + 3] * inv)};
      *(bf16x4*)(orow + d) = ov;
    }
}

extern "C" void kernel_launch(void* const* d_in, const int* in_sizes, int n_in,
                              void* d_out, int out_size, void* d_ws, size_t ws_size,
                              hipStream_t stream) {
  const float* x  = (const float*)d_in[0];
  // d_in[1] = mask (tril causal; hard-coded in kernel)
  const float* wq = (const float*)d_in[2];
  const float* bq = (const float*)d_in[3];
  const float* wk = (const float*)d_in[4];
  const float* bk = (const float*)d_in[5];
  const float* wv = (const float*)d_in[6];
  const float* bv = (const float*)d_in[7];
  const float* wo = (const float*)d_in[8];
  const float* bo = (const float*)d_in[9];
  float* out = (float*)d_out;

  const size_t MB = 1024 * 1024;
  char* ws = (char*)d_ws;
  __bf16* xb    = (__bf16*)(ws);             //  8 MiB: 2048x2048 (dead after QKV GEMM)
  __bf16* wqkvT = (__bf16*)(ws + 8 * MB);    // 24 MiB (dead after QKV GEMM)
  __bf16* woT   = (__bf16*)(ws + 32 * MB);   // 16 MiB: 2048x4096
  __bf16* qkvb  = (__bf16*)(ws + 48 * MB);   // 24 MiB: 2048x6144
  __bf16* vtb   = (__bf16*)(ws + 72 * MB);   //  4 MiB: 8x128x2048
  __bf16* ob    = (__bf16*)(ws + 76 * MB);   // 16 MiB: 2048x4096
  float*  bqkv  = (float*)(ws + 92 * MB);    // 24 KiB
  float*  Cpart = (float*)(ws);              // 32 MiB: 2x(2048x2048 f32), reuses xb+wqkvT

  k_cvt<<<4096, 256, 0, stream>>>(x, xb, HIDDEN * S_LEN);
  k_transpose_qkv<<<dim3(128, 64, 3), 256, 0, stream>>>(wq, wk, wv, wqkvT);
  k_transpose_cvt<<<dim3(64, 128), 256, 0, stream>>>(wo, woT, 4096, HIDDEN);
  k_bias_concat<<<24, 256, 0, stream>>>(bq, bk, bv, bqkv);

  // QKV projection: Q pre-scaled by log2(e)/sqrt(HD) so attention uses exp2
  k_gemm8<<<512, 256, 0, stream>>>(xb, wqkvT, bqkv, qkvb, S_LEN, QKVN, HIDDEN,
                                   0.12751743f, 4096);
  k_vtrans<<<dim3(S_LEN / 32, HD / 32, NKV), 256, 0, stream>>>(qkvb, vtb);
  k_attn<<<512, 256, 0, stream>>>(qkvb, vtb, ob);
  // O-projection: split-K=2, 2-phase counted-vmcnt dbuf (512 blocks = 2/CU)
  k_gemm_part<<<512, 256, 0, stream>>>(ob, woT, Cpart, S_LEN, HIDDEN, OD, OD / 2);
  k_ocombine<<<(S_LEN * HIDDEN) / 1024, 256, 0, stream>>>(
      Cpart, Cpart + (size_t)S_LEN * HIDDEN, bo, out);
}

// Round 19
// 213.385 us; speedup vs baseline: 1.0427x; 1.0427x over previous
//
#include <hip/hip_runtime.h>

#define HIDDEN 2048
#define S_LEN  2048
#define NH     32
#define NKV    8
#define HD     128
#define QKVN   6144   // 4096 q + 1024 k + 1024 v
#define OD     4096   // NH*HD

typedef float  f32x4   __attribute__((ext_vector_type(4)));
typedef float  f32x16  __attribute__((ext_vector_type(16)));
typedef __bf16 bf16x8  __attribute__((ext_vector_type(8)));
typedef __bf16 bf16x4  __attribute__((ext_vector_type(4)));
typedef unsigned int u32;

static __device__ __forceinline__ f32x4 mfma16(bf16x8 a, bf16x8 b, f32x4 c) {
  return __builtin_amdgcn_mfma_f32_16x16x32_bf16(a, b, c, 0, 0, 0);
}
static __device__ __forceinline__ f32x16 mfma32(bf16x8 a, bf16x8 b, f32x16 c) {
  return __builtin_amdgcn_mfma_f32_32x32x16_bf16(a, b, c, 0, 0, 0);
}
static __device__ __forceinline__ void gload_lds16(const void* g, void* l) {
  __builtin_amdgcn_global_load_lds(
      (__attribute__((address_space(1))) void*)(g),
      (__attribute__((address_space(3))) void*)(l), 16, 0, 0);
}
static __device__ __forceinline__ u32 pk_bf16(float lo, float hi) {
  u32 r;
  asm("v_cvt_pk_bf16_f32 %0, %1, %2" : "=v"(r) : "v"(lo), "v"(hi));
  return r;
}
// raw HW 2^x (v_exp_f32 IS exp2 on gfx9) — avoids libm exp2f's fix-up code
static __device__ __forceinline__ float hw_exp2(float x) {
  float r;
  asm("v_exp_f32 %0, %1" : "=v"(r) : "v"(x));
  return r;
}

// ---------- fp32 -> bf16 elementwise ----------
__global__ __launch_bounds__(256) void k_cvt(const float* __restrict__ in,
                                             __bf16* __restrict__ out, int n) {
  int i = (blockIdx.x * 256 + threadIdx.x) * 4;
  if (i >= n) return;
  float4 v = *reinterpret_cast<const float4*>(in + i);
  bf16x4 o = {(__bf16)v.x, (__bf16)v.y, (__bf16)v.z, (__bf16)v.w};
  *reinterpret_cast<bf16x4*>(out + i) = o;
}

// ---------- fused wq/wk/wv transpose+convert into wqkvT (z selects matrix) ----------
__global__ __launch_bounds__(256) void k_transpose_qkv(const float* __restrict__ wq,
                                                       const float* __restrict__ wk,
                                                       const float* __restrict__ wv,
                                                       __bf16* __restrict__ dst) {
  __shared__ float tile[32][33];
  const int z = blockIdx.z;
  const float* src = (z == 0) ? wq : (z == 1 ? wk : wv);
  const int Nsrc = (z == 0) ? 4096 : 1024;
  const int coff = (z == 0) ? 0 : (z == 1 ? 4096 : 5120);
  int tx = threadIdx.x & 31, ty = threadIdx.x >> 5;
  int n0 = blockIdx.x * 32, k0 = blockIdx.y * 32;
  if (n0 >= Nsrc) return;
#pragma unroll
  for (int r = 0; r < 4; r++) {
    int k = ty + r * 8;
    tile[k][tx] = src[(size_t)(k0 + k) * Nsrc + n0 + tx];
  }
  __syncthreads();
#pragma unroll
  for (int r = 0; r < 4; r++) {
    int n = ty + r * 8;
    dst[(size_t)(coff + n0 + n) * HIDDEN + k0 + tx] = (__bf16)tile[tx][n];
  }
}

// ---------- transpose + convert: src (K x N) f32 -> dst (N x K) bf16 ----------
__global__ __launch_bounds__(256) void k_transpose_cvt(const float* __restrict__ src,
                                                       __bf16* __restrict__ dst,
                                                       int K, int N) {
  __shared__ float tile[32][33];
  int tx = threadIdx.x & 31, ty = threadIdx.x >> 5;
  int n0 = blockIdx.x * 32, k0 = blockIdx.y * 32;
#pragma unroll
  for (int r = 0; r < 4; r++) {
    int k = ty + r * 8;
    tile[k][tx] = src[(size_t)(k0 + k) * N + n0 + tx];
  }
  __syncthreads();
#pragma unroll
  for (int r = 0; r < 4; r++) {
    int n = ty + r * 8;
    dst[(size_t)(n0 + n) * K + k0 + tx] = (__bf16)tile[tx][n];
  }
}

__global__ void k_bias_concat(const float* __restrict__ bq, const float* __restrict__ bk,
                              const float* __restrict__ bv, float* __restrict__ out) {
  int i = blockIdx.x * 256 + threadIdx.x;
  if (i >= QKVN) return;
  out[i] = (i < 4096) ? bq[i] : (i < 5120 ? bk[i - 4096] : bv[i - 5120]);
}

// ---------- V transpose: qkv (S x QKVN) v-cols -> vt (NKV x HD x S) ----------
__global__ __launch_bounds__(256) void k_vtrans(const __bf16* __restrict__ qkv,
                                                __bf16* __restrict__ vt) {
  __shared__ __bf16 tile[32][33];
  int tx = threadIdx.x & 31, ty = threadIdx.x >> 5;
  int s0 = blockIdx.x * 32, d0 = blockIdx.y * 32, kv = blockIdx.z;
#pragma unroll
  for (int r = 0; r < 4; r++) {
    int s = ty + r * 8;
    tile[s][tx] = qkv[(size_t)(s0 + s) * QKVN + 5120 + kv * HD + d0 + tx];
  }
  __syncthreads();
#pragma unroll
  for (int r = 0; r < 4; r++) {
    int d = ty + r * 8;
    vt[(size_t)(kv * HD + d0 + d) * S_LEN + s0 + tx] = tile[tx][d];
  }
}

// ---------- 128x192 BK=64 GEMM, 2 phases/K-tile, counted vmcnt (T2+T4+T5) ----------
__global__ __launch_bounds__(256, 2) void k_gemm8(const __bf16* __restrict__ A,
                                                  const __bf16* __restrict__ BT,
                                                  const float* __restrict__ bias,
                                                  __bf16* __restrict__ C,
                                                  int M, int N, int K,
                                                  float oscale, int scale_cols) {
  __shared__ __bf16 Al[2][2][4096];   // [dbuf][khalf][128 rows x 32 k]
  __shared__ __bf16 Bl[2][2][6144];   // [dbuf][khalf][192 rows x 32 k]
  const int tid = threadIdx.x, lane = tid & 63, w = tid >> 6;
  const int l15 = lane & 15, lhi = lane >> 4;
  const int sw = ((blockIdx.x & 7) << 6) + (blockIdx.x >> 3);  // XCD-chunked
  const int mt = sw & 15, nt = sw >> 4;
  const int m0 = mt * 128, n0 = nt * 192;
  const int NKT = K >> 6;
  const __bf16* Ab = A + (size_t)m0 * K;
  const __bf16* Bb = BT + (size_t)n0 * K;

  f32x4 acc[8][3];
#pragma unroll
  for (int i = 0; i < 8; i++)
#pragma unroll
    for (int j = 0; j < 3; j++)
#pragma unroll
      for (int e = 0; e < 4; e++) acc[i][j][e] = 0.f;

#define SGH(buf, kh, ktile)                                                       \
  do {                                                                            \
    _Pragma("unroll") for (int it = 0; it < 2; ++it) {                            \
      int c = it * 256 + tid;                                                     \
      int row = c >> 2, slot = c & 3;                                             \
      int scol = ((slot * 16) ^ (((row >> 1) & 3) << 4)) >> 1;                    \
      gload_lds16(Ab + (size_t)row * K + (ktile) * 64 + (kh) * 32 + scol,         \
                  &Al[buf][kh][c * 8]);                                           \
    }                                                                             \
    _Pragma("unroll") for (int it = 0; it < 3; ++it) {                            \
      int c = it * 256 + tid;                                                     \
      int row = c >> 2, slot = c & 3;                                             \
      int scol = ((slot * 16) ^ (((row >> 1) & 3) << 4)) >> 1;                    \
      gload_lds16(Bb + (size_t)row * K + (ktile) * 64 + (kh) * 32 + scol,         \
                  &Bl[buf][kh][c * 8]);                                           \
    }                                                                             \
  } while (0)

#define RD_AB(cb, kk)                                                             \
  do {                                                                            \
    _Pragma("unroll") for (int i = 0; i < 8; ++i) {                               \
      int row = i * 16 + l15;                                                     \
      af[i] = *(const bf16x8*)(&Al[cb][kk][row * 32 +                             \
                (((lhi * 16) ^ (((row >> 1) & 3) << 4)) >> 1)]);                  \
    }                                                                             \
    _Pragma("unroll") for (int j = 0; j < 3; ++j) {                               \
      int row = w * 48 + j * 16 + l15;                                            \
      bfr[j] = *(const bf16x8*)(&Bl[cb][kk][row * 32 +                            \
                (((lhi * 16) ^ (((row >> 1) & 3) << 4)) >> 1)]);                  \
    }                                                                             \
  } while (0)

#define MFMA24X                                                                   \
  do {                                                                            \
    __builtin_amdgcn_s_setprio(1);                                                \
    _Pragma("unroll") for (int i = 0; i < 8; ++i) {                               \
      _Pragma("unroll") for (int j = 0; j < 3; ++j) {                             \
        acc[i][j] = mfma16(af[i], bfr[j], acc[i][j]);                             \
      }                                                                           \
    }                                                                             \
    __builtin_amdgcn_s_setprio(0);                                                \
  } while (0)

  SGH(0, 0, 0);
  SGH(0, 1, 0);
  asm volatile("s_waitcnt vmcnt(5)" ::: "memory");
  __builtin_amdgcn_s_barrier();
  __builtin_amdgcn_sched_barrier(0);

  for (int kt = 0; kt < NKT; ++kt) {
    const int cb = kt & 1, pb = cb ^ 1;
    const bool pf = (kt + 1 < NKT);
    bf16x8 af[8], bfr[3];

    RD_AB(cb, 0);
    if (pf) SGH(pb, 0, kt + 1);
    __builtin_amdgcn_s_barrier();
    asm volatile("s_waitcnt lgkmcnt(0)" ::: "memory");
    MFMA24X;
    if (pf) {
      asm volatile("s_waitcnt vmcnt(5)" ::: "memory");
    } else {
      asm volatile("s_waitcnt vmcnt(0)" ::: "memory");
    }
    __builtin_amdgcn_s_barrier();
    __builtin_amdgcn_sched_barrier(0);

    RD_AB(cb, 1);
    if (pf) SGH(pb, 1, kt + 1);
    __builtin_amdgcn_s_barrier();
    asm volatile("s_waitcnt lgkmcnt(0)" ::: "memory");
    MFMA24X;
    if (pf) {
      asm volatile("s_waitcnt vmcnt(5)" ::: "memory");
    }
    __builtin_amdgcn_s_barrier();
    __builtin_amdgcn_sched_barrier(0);
  }
#undef SGH
#undef RD_AB
#undef MFMA24X

#pragma unroll
  for (int j = 0; j < 3; j++) {
    int col = n0 + w * 48 + j * 16 + l15;
    float bv = bias[col];
    float sc = (col < scale_cols) ? oscale : 1.0f;
#pragma unroll
    for (int i = 0; i < 8; i++) {
      int r0 = m0 + i * 16 + lhi * 4;
#pragma unroll
      for (int rr = 0; rr < 4; rr++) {
        C[(size_t)(r0 + rr) * N + col] = (__bf16)((acc[i][j][rr] + bv) * sc);
      }
    }
  }
}

// ---------- split-K O-GEMM partial, 2-phase counted-vmcnt dbuf ----------
__global__ __launch_bounds__(256, 2) void k_gemm_part(const __bf16* __restrict__ A,
                                                      const __bf16* __restrict__ BT,
                                                      float* __restrict__ Cpart,
                                                      int M, int N, int K, int KC) {
  __shared__ __bf16 Al[2][2][4096];   // [dbuf][khalf][128 rows x 32 k]
  __shared__ __bf16 Bl[2][2][4096];
  const int tid = threadIdx.x, lane = tid & 63, w = tid >> 6;
  const int l15 = lane & 15, lhi = lane >> 4;
  const int bid = blockIdx.x;
  const int z = bid >> 8, rem = bid & 255;
  const int sw = ((rem & 7) << 5) + (rem >> 3);  // XCD-chunked, bijective on 256
  const int mt = sw & 15, nt = sw >> 4;
  const int m0 = mt * 128, n0 = nt * 128;
  const int NKT = KC >> 6;
  const __bf16* Ab = A + (size_t)m0 * K + (size_t)z * KC;
  const __bf16* Bb = BT + (size_t)n0 * K + (size_t)z * KC;

  f32x4 acc[8][2];
#pragma unroll
  for (int i = 0; i < 8; i++)
#pragma unroll
    for (int j = 0; j < 2; j++)
#pragma unroll
      for (int e = 0; e < 4; e++) acc[i][j][e] = 0.f;

#define SGH2(buf, kh, ktile)                                                      \
  do {                                                                            \
    _Pragma("unroll") for (int it = 0; it < 2; ++it) {                            \
      int c = it * 256 + tid;                                                     \
      int row = c >> 2, slot = c & 3;                                             \
      int scol = ((slot * 16) ^ (((row >> 1) & 3) << 4)) >> 1;                    \
      gload_lds16(Ab + (size_t)row * K + (ktile) * 64 + (kh) * 32 + scol,         \
                  &Al[buf][kh][c * 8]);                                           \
    }                                                                             \
    _Pragma("unroll") for (int it = 0; it < 2; ++it) {                            \
      int c = it * 256 + tid;                                                     \
      int row = c >> 2, slot = c & 3;                                             \
      int scol = ((slot * 16) ^ (((row >> 1) & 3) << 4)) >> 1;                    \
      gload_lds16(Bb + (size_t)row * K + (ktile) * 64 + (kh) * 32 + scol,         \
                  &Bl[buf][kh][c * 8]);                                           \
    }                                                                             \
  } while (0)

#define RD_AB2(cb, kk)                                                            \
  do {                                                                            \
    _Pragma("unroll") for (int i = 0; i < 8; ++i) {                               \
      int row = i * 16 + l15;                                                     \
      af[i] = *(const bf16x8*)(&Al[cb][kk][row * 32 +                             \
                (((lhi * 16) ^ (((row >> 1) & 3) << 4)) >> 1)]);                  \
    }                                                                             \
    _Pragma("unroll") for (int j = 0; j < 2; ++j) {                               \
      int row = w * 32 + j * 16 + l15;                                            \
      bfr[j] = *(const bf16x8*)(&Bl[cb][kk][row * 32 +                            \
                (((lhi * 16) ^ (((row >> 1) & 3) << 4)) >> 1)]);                  \
    }                                                                             \
  } while (0)

#define MFMA16X                                                                   \
  do {                                                                            \
    __builtin_amdgcn_s_setprio(1);                                                \
    _Pragma("unroll") for (int i = 0; i < 8; ++i) {                               \
      _Pragma("unroll") for (int j = 0; j < 2; ++j) {                             \
        acc[i][j] = mfma16(af[i], bfr[j], acc[i][j]);                             \
      }                                                                           \
    }                                                                             \
    __builtin_amdgcn_s_setprio(0);                                                \
  } while (0)

  SGH2(0, 0, 0);
  SGH2(0, 1, 0);
  asm volatile("s_waitcnt vmcnt(4)" ::: "memory");
  __builtin_amdgcn_s_barrier();
  __builtin_amdgcn_sched_barrier(0);

  for (int kt = 0; kt < NKT; ++kt) {
    const int cb = kt & 1, pb = cb ^ 1;
    const bool pf = (kt + 1 < NKT);
    bf16x8 af[8], bfr[2];

    RD_AB2(cb, 0);
    if (pf) SGH2(pb, 0, kt + 1);
    __builtin_amdgcn_s_barrier();
    asm volatile("s_waitcnt lgkmcnt(0)" ::: "memory");
    MFMA16X;
    if (pf) {
      asm volatile("s_waitcnt vmcnt(4)" ::: "memory");
    } else {
      asm volatile("s_waitcnt vmcnt(0)" ::: "memory");
    }
    __builtin_amdgcn_s_barrier();
    __builtin_amdgcn_sched_barrier(0);

    RD_AB2(cb, 1);
    if (pf) SGH2(pb, 1, kt + 1);
    __builtin_amdgcn_s_barrier();
    asm volatile("s_waitcnt lgkmcnt(0)" ::: "memory");
    MFMA16X;
    if (pf) {
      asm volatile("s_waitcnt vmcnt(4)" ::: "memory");
    }
    __builtin_amdgcn_s_barrier();
    __builtin_amdgcn_sched_barrier(0);
  }
#undef SGH2
#undef RD_AB2
#undef MFMA16X

  float* C = Cpart + (size_t)z * M * N;
#pragma unroll
  for (int j = 0; j < 2; j++) {
    int col = n0 + w * 32 + j * 16 + l15;
#pragma unroll
    for (int i = 0; i < 8; i++) {
      int r0 = m0 + i * 16 + lhi * 4;
#pragma unroll
      for (int rr = 0; rr < 4; rr++) {
        C[(size_t)(r0 + rr) * N + col] = acc[i][j][rr];
      }
    }
  }
}

// ---------- combine split-K partials + bias -> f32 out ----------
__global__ __launch_bounds__(256) void k_ocombine(const float* __restrict__ a,
                                                  const float* __restrict__ b,
                                                  const float* __restrict__ bias,
                                                  float* __restrict__ out) {
  int i = (blockIdx.x * 256 + threadIdx.x) * 4;
  f32x4 va = *(const f32x4*)(a + i);
  f32x4 vb = *(const f32x4*)(b + i);
  f32x4 vbias = *(const f32x4*)(bias + (i & (HIDDEN - 1)));
  f32x4 r = va + vb + vbias;
  *(f32x4*)(out + i) = r;
}

// ---------- causal GQA flash attention (exp2 softmax via raw v_exp_f32) ----------
// 512 blocks, 256 threads; ids i and i+256 get tiles t and 15-t. 4 waves x 32
// q-rows. Double-buffered K/V (64 KiB), coalesced staging, pre-swizzled source
// (rule #21). Q pre-scaled by (1/sqrt(d))*log2(e) in the QKV GEMM epilogue;
// softmax uses raw v_exp_f32 (2^x in HW) via inline asm — exp2f() libm adds
// range-fixup VALU ops (r18 regression), __expf adds a ln2-mul (pre-r18).
// Row max and sum are depth-5 trees. S^T = mfma(K,Q) so q = lane&31;
// P in registers via cvt_pk + permlane32_swap; O^T = mfma(V^T, P).
//   Kl[key][d]: byte = key*256 + ((2d) ^ ((key&15)<<4))   (reads 2-way, free)
//   Vl[d][k]:   byte = d*128  + ((2k) ^ ((d&7)<<4))       (reads 4-way, 1.58x)
__global__ __launch_bounds__(256, 2) void k_attn(const __bf16* __restrict__ qkv,
                                                 const __bf16* __restrict__ vt,
                                                 __bf16* __restrict__ o) {
  __shared__ __bf16 Kl[2][8192];
  __shared__ __bf16 Vl[2][8192];
  const int tid = threadIdx.x, lane = tid & 63, w = tid >> 6;
  const int l31 = lane & 31, h = lane >> 5;

  // block-id pairing: ids i and i+256 get tiles t and 15-t (uniform CU load)
  const int id = blockIdx.x;
  int tile, head;
  if (id < 256) { head = id >> 4; tile = id & 15; }
  else          { head = 16 + ((id - 256) >> 4); tile = 15 - (id & 15); }
  const int kvh = head >> 2;
  const int qbase = tile * 128 + w * 32;
  const int qg = qbase + l31;          // this lane's q row
  const int kdiag = (qbase + 31) >> 6; // last (partial) key tile for this wave
  const int nkt = 2 * tile + 2;

  // Q fragments (pre-scaled by log2e/sqrt(d) in QKV GEMM epilogue): B-frag col=q
  bf16x8 qf[8];
  {
    const __bf16* qrow = qkv + (size_t)qg * QKVN + head * HD;
#pragma unroll
    for (int dk = 0; dk < 8; dk++) qf[dk] = *(const bf16x8*)(qrow + dk * 16 + h * 8);
  }

  f32x16 acc[4];  // O^T: col=q=lane&31, row=d (reg-mapped), dt*32 block
#pragma unroll
  for (int dt = 0; dt < 4; dt++)
#pragma unroll
    for (int r = 0; r < 16; r++) acc[dt][r] = 0.f;
  float m = -INFINITY, lsum = 0.f;

#define STAGE(buf, ktile)                                                           \
  do {                                                                              \
    const int kk0 = (ktile) * 64;                                                   \
    _Pragma("unroll") for (int it = 0; it < 4; it++) {                              \
      int c = it * 256 + tid;                                                       \
      int key = c >> 4, slot = c & 15;                                              \
      int scol = ((slot * 16) ^ ((key & 15) << 4)) >> 1;                            \
      gload_lds16(qkv + (size_t)(kk0 + key) * QKVN + 4096 + kvh * HD + scol,        \
                  &Kl[buf][c * 8]);                                                 \
    }                                                                               \
    _Pragma("unroll") for (int it = 0; it < 4; it++) {                              \
      int c = it * 256 + tid;                                                       \
      int d = c >> 3, slot = c & 7;                                                 \
      int scol = ((slot * 16) ^ ((d & 7) << 4)) >> 1;                               \
      gload_lds16(vt + (size_t)(kvh * HD + d) * S_LEN + kk0 + scol,                 \
                  &Vl[buf][c * 8]);                                                 \
    }                                                                               \
  } while (0)

  STAGE(0, 0);
  __syncthreads();

  for (int kt = 0; kt < nkt; kt++) {
    const int cur = kt & 1;
    if (kt + 1 < nkt) STAGE(cur ^ 1, kt + 1);  // in flight during compute

    if (kt <= kdiag) {
      const char* Kb = (const char*)&Kl[cur][0];
      const char* Vb = (const char*)&Vl[cur][0];
      const int k0 = kt * 64;
      // ---- QK^T: S^T[key][q], two 32-key blocks ----
      f32x16 sacc[2];
#pragma unroll
      for (int b = 0; b < 2; b++)
#pragma unroll
        for (int r = 0; r < 16; r++) sacc[b][r] = 0.f;
      __builtin_amdgcn_s_setprio(1);
#pragma unroll
      for (int dk = 0; dk < 8; dk++) {
        const int sA = ((2 * dk + h) ^ (l31 & 15)) * 16;
        bf16x8 kf0 = *(const bf16x8*)(Kb + l31 * 256 + sA);
        bf16x8 kf1 = *(const bf16x8*)(Kb + (32 + l31) * 256 + sA);
        sacc[0] = mfma32(kf0, qf[dk], sacc[0]);
        sacc[1] = mfma32(kf1, qf[dk], sacc[1]);
      }
      __builtin_amdgcn_s_setprio(0);
      // ---- softmax in log2 domain (lane-local; q = lane&31) ----
      float p[32];
#pragma unroll
      for (int b = 0; b < 2; b++)
#pragma unroll
        for (int r = 0; r < 16; r++) p[b * 16 + r] = sacc[b][r];
      if (kt == kdiag) {  // mask only on the diagonal tile
#pragma unroll
        for (int b = 0; b < 2; b++)
#pragma unroll
          for (int r = 0; r < 16; r++) {
            int keyg = k0 + b * 32 + (r & 3) + 8 * (r >> 2) + 4 * h;
            if (keyg > qg) p[b * 16 + r] = -INFINITY;
          }
      }
      // pairwise max tree (depth 5)
      float t16[16], t8[8], t4[4];
#pragma unroll
      for (int i = 0; i < 16; i++) t16[i] = fmaxf(p[2 * i], p[2 * i + 1]);
#pragma unroll
      for (int i = 0; i < 8; i++) t8[i] = fmaxf(t16[2 * i], t16[2 * i + 1]);
#pragma unroll
      for (int i = 0; i < 4; i++) t4[i] = fmaxf(t8[2 * i], t8[2 * i + 1]);
      float pm = fmaxf(fmaxf(t4[0], t4[1]), fmaxf(t4[2], t4[3]));
      pm = fmaxf(pm, __shfl_xor(pm, 32));
      if (__any(pm - m > 8.f)) {  // defer-max (T13), log2 units
        float mn = fmaxf(m, pm);
        float corr = hw_exp2(m - mn);
        m = mn;
        lsum *= corr;
#pragma unroll
        for (int dt = 0; dt < 4; dt++)
#pragma unroll
          for (int r = 0; r < 16; r++) acc[dt][r] *= corr;
      }
      // p = 2^(s - m) via raw v_exp_f32; row-sum as depth-5 tree
#pragma unroll
      for (int i = 0; i < 32; i++) p[i] = hw_exp2(p[i] - m);
      float u16[16], u8[8], u4[4];
#pragma unroll
      for (int i = 0; i < 16; i++) u16[i] = p[2 * i] + p[2 * i + 1];
#pragma unroll
      for (int i = 0; i < 8; i++) u8[i] = u16[2 * i] + u16[2 * i + 1];
#pragma unroll
      for (int i = 0; i < 4; i++) u4[i] = u8[2 * i] + u8[2 * i + 1];
      lsum += (u4[0] + u4[1]) + (u4[2] + u4[3]);
      // ---- PV: O^T += V^T * P, P-frags built in-register ----
      // permlane32_swap(W0,W2): W0 -> {lo:W0@h0, hi:W2@h0}, W2 -> {lo:W0@h1, hi:W2@h1}.
#pragma unroll
      for (int ks2 = 0; ks2 < 4; ks2++) {
        const int o8 = (ks2 >> 1) * 16 + (ks2 & 1) * 8;
        u32 W0 = pk_bf16(p[o8 + 0], p[o8 + 1]);
        u32 W1 = pk_bf16(p[o8 + 2], p[o8 + 3]);
        u32 W2 = pk_bf16(p[o8 + 4], p[o8 + 5]);
        u32 W3 = pk_bf16(p[o8 + 6], p[o8 + 7]);
        asm("v_permlane32_swap_b32 %0, %1" : "+v"(W0), "+v"(W2));
        asm("v_permlane32_swap_b32 %0, %1" : "+v"(W1), "+v"(W3));
        union { u32 wd[4]; bf16x8 v; } pu;
        pu.wd[0] = W0; pu.wd[1] = W1; pu.wd[2] = W2; pu.wd[3] = W3;
        __builtin_amdgcn_s_setprio(1);
#pragma unroll
        for (int dt = 0; dt < 4; dt++) {
          const int dr = dt * 32 + l31;
          const int sV = ((2 * ks2 + h) ^ (dr & 7)) * 16;
          bf16x8 vf = *(const bf16x8*)(Vb + dr * 128 + sV);
          acc[dt] = mfma32(vf, pu.v, acc[dt]);
        }
        __builtin_amdgcn_s_setprio(0);
      }
    }
    __syncthreads();  // drains vmcnt: next tile landed; buffers safe to swap
  }
#undef STAGE

  // ---- finalize: combine the two key-halves, normalize, store ----
  lsum += __shfl_xor(lsum, 32);
  const float inv = 1.f / lsum;
  __bf16* orow = o + (size_t)qg * OD + head * HD;
#pragma unroll
  for (int dt = 0; dt < 4; dt++)
#pragma unroll
    for (int rq = 0; rq < 4; rq++) {  // reg quads -> 4 consecutive d
      int d = dt * 32 + 8 * rq + 4 * h;
      bf16x4 ov = {(__bf16)(acc[dt][rq * 4 + 0] * inv), (__bf16)(acc[dt][rq * 4 + 1] * inv),
                   (__bf16)(acc[dt][rq * 4 + 2] * inv), (__bf16)(acc[dt][rq * 4 + 3] * inv)};
      *(bf16x4*)(orow + d) = ov;
    }
}

extern "C" void kernel_launch(void* const* d_in, const int* in_sizes, int n_in,
                              void* d_out, int out_size, void* d_ws, size_t ws_size,
                              hipStream_t stream) {
  const float* x  = (const float*)d_in[0];
  // d_in[1] = mask (tril causal; hard-coded in kernel)
  const float* wq = (const float*)d_in[2];
  const float* bq = (const float*)d_in[3];
  const float* wk = (const float*)d_in[4];
  const float* bk = (const float*)d_in[5];
  const float* wv = (const float*)d_in[6];
  const float* bv = (const float*)d_in[7];
  const float* wo = (const float*)d_in[8];
  const float* bo = (const float*)d_in[9];
  float* out = (float*)d_out;

  const size_t MB = 1024 * 1024;
  char* ws = (char*)d_ws;
  __bf16* xb    = (__bf16*)(ws);             //  8 MiB: 2048x2048 (dead after QKV GEMM)
  __bf16* wqkvT = (__bf16*)(ws + 8 * MB);    // 24 MiB (dead after QKV GEMM)
  __bf16* woT   = (__bf16*)(ws + 32 * MB);   // 16 MiB: 2048x4096
  __bf16* qkvb  = (__bf16*)(ws + 48 * MB);   // 24 MiB: 2048x6144
  __bf16* vtb   = (__bf16*)(ws + 72 * MB);   //  4 MiB: 8x128x2048
  __bf16* ob    = (__bf16*)(ws + 76 * MB);   // 16 MiB: 2048x4096
  float*  bqkv  = (float*)(ws + 92 * MB);    // 24 KiB
  float*  Cpart = (float*)(ws);              // 32 MiB: 2x(2048x2048 f32), reuses xb+wqkvT

  k_cvt<<<4096, 256, 0, stream>>>(x, xb, HIDDEN * S_LEN);
  k_transpose_qkv<<<dim3(128, 64, 3), 256, 0, stream>>>(wq, wk, wv, wqkvT);
  k_transpose_cvt<<<dim3(64, 128), 256, 0, stream>>>(wo, woT, 4096, HIDDEN);
  k_bias_concat<<<24, 256, 0, stream>>>(bq, bk, bv, bqkv);

  // QKV projection: Q pre-scaled by log2(e)/sqrt(HD) so attention uses exp2
  k_gemm8<<<512, 256, 0, stream>>>(xb, wqkvT, bqkv, qkvb, S_LEN, QKVN, HIDDEN,
                                   0.12751743f, 4096);
  k_vtrans<<<dim3(S_LEN / 32, HD / 32, NKV), 256, 0, stream>>>(qkvb, vtb);
  k_attn<<<512, 256, 0, stream>>>(qkvb, vtb, ob);
  // O-projection: split-K=2, 2-phase counted-vmcnt dbuf (512 blocks = 2/CU)
  k_gemm_part<<<512, 256, 0, stream>>>(ob, woT, Cpart, S_LEN, HIDDEN, OD, OD / 2);
  k_ocombine<<<(S_LEN * HIDDEN) / 1024, 256, 0, stream>>>(
      Cpart, Cpart + (size_t)S_LEN * HIDDEN, bo, out);
}

// Round 20
// 212.244 us; speedup vs baseline: 1.0483x; 1.0054x over previous
//
#include <hip/hip_runtime.h>

#define HIDDEN 2048
#define S_LEN  2048
#define NH     32
#define NKV    8
#define HD     128
#define QKVN   6144   // 4096 q + 1024 k + 1024 v
#define OD     4096   // NH*HD

typedef float  f32x4   __attribute__((ext_vector_type(4)));
typedef float  f32x16  __attribute__((ext_vector_type(16)));
typedef __bf16 bf16x8  __attribute__((ext_vector_type(8)));
typedef __bf16 bf16x4  __attribute__((ext_vector_type(4)));
typedef unsigned int u32;

static __device__ __forceinline__ f32x4 mfma16(bf16x8 a, bf16x8 b, f32x4 c) {
  return __builtin_amdgcn_mfma_f32_16x16x32_bf16(a, b, c, 0, 0, 0);
}
static __device__ __forceinline__ f32x16 mfma32(bf16x8 a, bf16x8 b, f32x16 c) {
  return __builtin_amdgcn_mfma_f32_32x32x16_bf16(a, b, c, 0, 0, 0);
}
static __device__ __forceinline__ void gload_lds16(const void* g, void* l) {
  __builtin_amdgcn_global_load_lds(
      (__attribute__((address_space(1))) void*)(g),
      (__attribute__((address_space(3))) void*)(l), 16, 0, 0);
}
static __device__ __forceinline__ u32 pk_bf16(float lo, float hi) {
  u32 r;
  asm("v_cvt_pk_bf16_f32 %0, %1, %2" : "=v"(r) : "v"(lo), "v"(hi));
  return r;
}
// raw HW 2^x (v_exp_f32 IS exp2 on gfx9) — avoids libm exp2f's fix-up code
static __device__ __forceinline__ float hw_exp2(float x) {
  float r;
  asm("v_exp_f32 %0, %1" : "=v"(r) : "v"(x));
  return r;
}

// ---------- fp32 -> bf16 elementwise ----------
__global__ __launch_bounds__(256) void k_cvt(const float* __restrict__ in,
                                             __bf16* __restrict__ out, int n) {
  int i = (blockIdx.x * 256 + threadIdx.x) * 4;
  if (i >= n) return;
  float4 v = *reinterpret_cast<const float4*>(in + i);
  bf16x4 o = {(__bf16)v.x, (__bf16)v.y, (__bf16)v.z, (__bf16)v.w};
  *reinterpret_cast<bf16x4*>(out + i) = o;
}

// ---------- fused wq/wk/wv transpose+convert into wqkvT (z selects matrix) ----------
__global__ __launch_bounds__(256) void k_transpose_qkv(const float* __restrict__ wq,
                                                       const float* __restrict__ wk,
                                                       const float* __restrict__ wv,
                                                       __bf16* __restrict__ dst) {
  __shared__ float tile[32][33];
  const int z = blockIdx.z;
  const float* src = (z == 0) ? wq : (z == 1 ? wk : wv);
  const int Nsrc = (z == 0) ? 4096 : 1024;
  const int coff = (z == 0) ? 0 : (z == 1 ? 4096 : 5120);
  int tx = threadIdx.x & 31, ty = threadIdx.x >> 5;
  int n0 = blockIdx.x * 32, k0 = blockIdx.y * 32;
  if (n0 >= Nsrc) return;
#pragma unroll
  for (int r = 0; r < 4; r++) {
    int k = ty + r * 8;
    tile[k][tx] = src[(size_t)(k0 + k) * Nsrc + n0 + tx];
  }
  __syncthreads();
#pragma unroll
  for (int r = 0; r < 4; r++) {
    int n = ty + r * 8;
    dst[(size_t)(coff + n0 + n) * HIDDEN + k0 + tx] = (__bf16)tile[tx][n];
  }
}

// ---------- transpose + convert: src (K x N) f32 -> dst (N x K) bf16 ----------
__global__ __launch_bounds__(256) void k_transpose_cvt(const float* __restrict__ src,
                                                       __bf16* __restrict__ dst,
                                                       int K, int N) {
  __shared__ float tile[32][33];
  int tx = threadIdx.x & 31, ty = threadIdx.x >> 5;
  int n0 = blockIdx.x * 32, k0 = blockIdx.y * 32;
#pragma unroll
  for (int r = 0; r < 4; r++) {
    int k = ty + r * 8;
    tile[k][tx] = src[(size_t)(k0 + k) * N + n0 + tx];
  }
  __syncthreads();
#pragma unroll
  for (int r = 0; r < 4; r++) {
    int n = ty + r * 8;
    dst[(size_t)(n0 + n) * K + k0 + tx] = (__bf16)tile[tx][n];
  }
}

__global__ void k_bias_concat(const float* __restrict__ bq, const float* __restrict__ bk,
                              const float* __restrict__ bv, float* __restrict__ out) {
  int i = blockIdx.x * 256 + threadIdx.x;
  if (i >= QKVN) return;
  out[i] = (i < 4096) ? bq[i] : (i < 5120 ? bk[i - 4096] : bv[i - 5120]);
}

// ---------- V transpose: qkv (S x QKVN) v-cols -> vt (NKV x HD x S) ----------
__global__ __launch_bounds__(256) void k_vtrans(const __bf16* __restrict__ qkv,
                                                __bf16* __restrict__ vt) {
  __shared__ __bf16 tile[32][33];
  int tx = threadIdx.x & 31, ty = threadIdx.x >> 5;
  int s0 = blockIdx.x * 32, d0 = blockIdx.y * 32, kv = blockIdx.z;
#pragma unroll
  for (int r = 0; r < 4; r++) {
    int s = ty + r * 8;
    tile[s][tx] = qkv[(size_t)(s0 + s) * QKVN + 5120 + kv * HD + d0 + tx];
  }
  __syncthreads();
#pragma unroll
  for (int r = 0; r < 4; r++) {
    int d = ty + r * 8;
    vt[(size_t)(kv * HD + d0 + d) * S_LEN + s0 + tx] = tile[tx][d];
  }
}

// ---------- 128x192 BK=64 GEMM, 2 phases/K-tile, counted vmcnt (T2+T4+T5) ----------
__global__ __launch_bounds__(256, 2) void k_gemm8(const __bf16* __restrict__ A,
                                                  const __bf16* __restrict__ BT,
                                                  const float* __restrict__ bias,
                                                  __bf16* __restrict__ C,
                                                  int M, int N, int K,
                                                  float oscale, int scale_cols) {
  __shared__ __bf16 Al[2][2][4096];   // [dbuf][khalf][128 rows x 32 k]
  __shared__ __bf16 Bl[2][2][6144];   // [dbuf][khalf][192 rows x 32 k]
  const int tid = threadIdx.x, lane = tid & 63, w = tid >> 6;
  const int l15 = lane & 15, lhi = lane >> 4;
  const int sw = ((blockIdx.x & 7) << 6) + (blockIdx.x >> 3);  // XCD-chunked
  const int mt = sw & 15, nt = sw >> 4;
  const int m0 = mt * 128, n0 = nt * 192;
  const int NKT = K >> 6;
  const __bf16* Ab = A + (size_t)m0 * K;
  const __bf16* Bb = BT + (size_t)n0 * K;

  f32x4 acc[8][3];
#pragma unroll
  for (int i = 0; i < 8; i++)
#pragma unroll
    for (int j = 0; j < 3; j++)
#pragma unroll
      for (int e = 0; e < 4; e++) acc[i][j][e] = 0.f;

#define SGH(buf, kh, ktile)                                                       \
  do {                                                                            \
    _Pragma("unroll") for (int it = 0; it < 2; ++it) {                            \
      int c = it * 256 + tid;                                                     \
      int row = c >> 2, slot = c & 3;                                             \
      int scol = ((slot * 16) ^ (((row >> 1) & 3) << 4)) >> 1;                    \
      gload_lds16(Ab + (size_t)row * K + (ktile) * 64 + (kh) * 32 + scol,         \
                  &Al[buf][kh][c * 8]);                                           \
    }                                                                             \
    _Pragma("unroll") for (int it = 0; it < 3; ++it) {                            \
      int c = it * 256 + tid;                                                     \
      int row = c >> 2, slot = c & 3;                                             \
      int scol = ((slot * 16) ^ (((row >> 1) & 3) << 4)) >> 1;                    \
      gload_lds16(Bb + (size_t)row * K + (ktile) * 64 + (kh) * 32 + scol,         \
                  &Bl[buf][kh][c * 8]);                                           \
    }                                                                             \
  } while (0)

#define RD_AB(cb, kk)                                                             \
  do {                                                                            \
    _Pragma("unroll") for (int i = 0; i < 8; ++i) {                               \
      int row = i * 16 + l15;                                                     \
      af[i] = *(const bf16x8*)(&Al[cb][kk][row * 32 +                             \
                (((lhi * 16) ^ (((row >> 1) & 3) << 4)) >> 1)]);                  \
    }                                                                             \
    _Pragma("unroll") for (int j = 0; j < 3; ++j) {                               \
      int row = w * 48 + j * 16 + l15;                                            \
      bfr[j] = *(const bf16x8*)(&Bl[cb][kk][row * 32 +                            \
                (((lhi * 16) ^ (((row >> 1) & 3) << 4)) >> 1)]);                  \
    }                                                                             \
  } while (0)

#define MFMA24X                                                                   \
  do {                                                                            \
    __builtin_amdgcn_s_setprio(1);                                                \
    _Pragma("unroll") for (int i = 0; i < 8; ++i) {                               \
      _Pragma("unroll") for (int j = 0; j < 3; ++j) {                             \
        acc[i][j] = mfma16(af[i], bfr[j], acc[i][j]);                             \
      }                                                                           \
    }                                                                             \
    __builtin_amdgcn_s_setprio(0);                                                \
  } while (0)

  SGH(0, 0, 0);
  SGH(0, 1, 0);
  asm volatile("s_waitcnt vmcnt(5)" ::: "memory");
  __builtin_amdgcn_s_barrier();
  __builtin_amdgcn_sched_barrier(0);

  for (int kt = 0; kt < NKT; ++kt) {
    const int cb = kt & 1, pb = cb ^ 1;
    const bool pf = (kt + 1 < NKT);
    bf16x8 af[8], bfr[3];

    RD_AB(cb, 0);
    if (pf) SGH(pb, 0, kt + 1);
    __builtin_amdgcn_s_barrier();
    asm volatile("s_waitcnt lgkmcnt(0)" ::: "memory");
    MFMA24X;
    if (pf) {
      asm volatile("s_waitcnt vmcnt(5)" ::: "memory");
    } else {
      asm volatile("s_waitcnt vmcnt(0)" ::: "memory");
    }
    __builtin_amdgcn_s_barrier();
    __builtin_amdgcn_sched_barrier(0);

    RD_AB(cb, 1);
    if (pf) SGH(pb, 1, kt + 1);
    __builtin_amdgcn_s_barrier();
    asm volatile("s_waitcnt lgkmcnt(0)" ::: "memory");
    MFMA24X;
    if (pf) {
      asm volatile("s_waitcnt vmcnt(5)" ::: "memory");
    }
    __builtin_amdgcn_s_barrier();
    __builtin_amdgcn_sched_barrier(0);
  }
#undef SGH
#undef RD_AB
#undef MFMA24X

#pragma unroll
  for (int j = 0; j < 3; j++) {
    int col = n0 + w * 48 + j * 16 + l15;
    float bv = bias[col];
    float sc = (col < scale_cols) ? oscale : 1.0f;
#pragma unroll
    for (int i = 0; i < 8; i++) {
      int r0 = m0 + i * 16 + lhi * 4;
#pragma unroll
      for (int rr = 0; rr < 4; rr++) {
        C[(size_t)(r0 + rr) * N + col] = (__bf16)((acc[i][j][rr] + bv) * sc);
      }
    }
  }
}

// ---------- split-K O-GEMM partial, 2-phase counted-vmcnt dbuf ----------
__global__ __launch_bounds__(256, 2) void k_gemm_part(const __bf16* __restrict__ A,
                                                      const __bf16* __restrict__ BT,
                                                      float* __restrict__ Cpart,
                                                      int M, int N, int K, int KC) {
  __shared__ __bf16 Al[2][2][4096];   // [dbuf][khalf][128 rows x 32 k]
  __shared__ __bf16 Bl[2][2][4096];
  const int tid = threadIdx.x, lane = tid & 63, w = tid >> 6;
  const int l15 = lane & 15, lhi = lane >> 4;
  const int bid = blockIdx.x;
  const int z = bid >> 8, rem = bid & 255;
  const int sw = ((rem & 7) << 5) + (rem >> 3);  // XCD-chunked, bijective on 256
  const int mt = sw & 15, nt = sw >> 4;
  const int m0 = mt * 128, n0 = nt * 128;
  const int NKT = KC >> 6;
  const __bf16* Ab = A + (size_t)m0 * K + (size_t)z * KC;
  const __bf16* Bb = BT + (size_t)n0 * K + (size_t)z * KC;

  f32x4 acc[8][2];
#pragma unroll
  for (int i = 0; i < 8; i++)
#pragma unroll
    for (int j = 0; j < 2; j++)
#pragma unroll
      for (int e = 0; e < 4; e++) acc[i][j][e] = 0.f;

#define SGH2(buf, kh, ktile)                                                      \
  do {                                                                            \
    _Pragma("unroll") for (int it = 0; it < 2; ++it) {                            \
      int c = it * 256 + tid;                                                     \
      int row = c >> 2, slot = c & 3;                                             \
      int scol = ((slot * 16) ^ (((row >> 1) & 3) << 4)) >> 1;                    \
      gload_lds16(Ab + (size_t)row * K + (ktile) * 64 + (kh) * 32 + scol,         \
                  &Al[buf][kh][c * 8]);                                           \
    }                                                                             \
    _Pragma("unroll") for (int it = 0; it < 2; ++it) {                            \
      int c = it * 256 + tid;                                                     \
      int row = c >> 2, slot = c & 3;                                             \
      int scol = ((slot * 16) ^ (((row >> 1) & 3) << 4)) >> 1;                    \
      gload_lds16(Bb + (size_t)row * K + (ktile) * 64 + (kh) * 32 + scol,         \
                  &Bl[buf][kh][c * 8]);                                           \
    }                                                                             \
  } while (0)

#define RD_AB2(cb, kk)                                                            \
  do {                                                                            \
    _Pragma("unroll") for (int i = 0; i < 8; ++i) {                               \
      int row = i * 16 + l15;                                                     \
      af[i] = *(const bf16x8*)(&Al[cb][kk][row * 32 +                             \
                (((lhi * 16) ^ (((row >> 1) & 3) << 4)) >> 1)]);                  \
    }                                                                             \
    _Pragma("unroll") for (int j = 0; j < 2; ++j) {                               \
      int row = w * 32 + j * 16 + l15;                                            \
      bfr[j] = *(const bf16x8*)(&Bl[cb][kk][row * 32 +                            \
                (((lhi * 16) ^ (((row >> 1) & 3) << 4)) >> 1)]);                  \
    }                                                                             \
  } while (0)

#define MFMA16X                                                                   \
  do {                                                                            \
    __builtin_amdgcn_s_setprio(1);                                                \
    _Pragma("unroll") for (int i = 0; i < 8; ++i) {                               \
      _Pragma("unroll") for (int j = 0; j < 2; ++j) {                             \
        acc[i][j] = mfma16(af[i], bfr[j], acc[i][j]);                             \
      }                                                                           \
    }                                                                             \
    __builtin_amdgcn_s_setprio(0);                                                \
  } while (0)

  SGH2(0, 0, 0);
  SGH2(0, 1, 0);
  asm volatile("s_waitcnt vmcnt(4)" ::: "memory");
  __builtin_amdgcn_s_barrier();
  __builtin_amdgcn_sched_barrier(0);

  for (int kt = 0; kt < NKT; ++kt) {
    const int cb = kt & 1, pb = cb ^ 1;
    const bool pf = (kt + 1 < NKT);
    bf16x8 af[8], bfr[2];

    RD_AB2(cb, 0);
    if (pf) SGH2(pb, 0, kt + 1);
    __builtin_amdgcn_s_barrier();
    asm volatile("s_waitcnt lgkmcnt(0)" ::: "memory");
    MFMA16X;
    if (pf) {
      asm volatile("s_waitcnt vmcnt(4)" ::: "memory");
    } else {
      asm volatile("s_waitcnt vmcnt(0)" ::: "memory");
    }
    __builtin_amdgcn_s_barrier();
    __builtin_amdgcn_sched_barrier(0);

    RD_AB2(cb, 1);
    if (pf) SGH2(pb, 1, kt + 1);
    __builtin_amdgcn_s_barrier();
    asm volatile("s_waitcnt lgkmcnt(0)" ::: "memory");
    MFMA16X;
    if (pf) {
      asm volatile("s_waitcnt vmcnt(4)" ::: "memory");
    }
    __builtin_amdgcn_s_barrier();
    __builtin_amdgcn_sched_barrier(0);
  }
#undef SGH2
#undef RD_AB2
#undef MFMA16X

  float* C = Cpart + (size_t)z * M * N;
#pragma unroll
  for (int j = 0; j < 2; j++) {
    int col = n0 + w * 32 + j * 16 + l15;
#pragma unroll
    for (int i = 0; i < 8; i++) {
      int r0 = m0 + i * 16 + lhi * 4;
#pragma unroll
      for (int rr = 0; rr < 4; rr++) {
        C[(size_t)(r0 + rr) * N + col] = acc[i][j][rr];
      }
    }
  }
}

// ---------- combine split-K partials + bias -> f32 out ----------
__global__ __launch_bounds__(256) void k_ocombine(const float* __restrict__ a,
                                                  const float* __restrict__ b,
                                                  const float* __restrict__ bias,
                                                  float* __restrict__ out) {
  int i = (blockIdx.x * 256 + threadIdx.x) * 4;
  f32x4 va = *(const f32x4*)(a + i);
  f32x4 vb = *(const f32x4*)(b + i);
  f32x4 vbias = *(const f32x4*)(bias + (i & (HIDDEN - 1)));
  f32x4 r = va + vb + vbias;
  *(f32x4*)(out + i) = r;
}

// ---------- causal GQA flash attention (exp2 softmax via raw v_exp_f32) ----------
// 512 blocks, 256 threads; ids i and i+256 get tiles t and 15-t. 4 waves x 32
// q-rows. Double-buffered K/V (64 KiB), coalesced staging, pre-swizzled source
// (rule #21). Q pre-scaled by (1/sqrt(d))*log2(e) in the QKV GEMM epilogue;
// softmax uses raw v_exp_f32 (2^x in HW) via inline asm — exp2f() libm adds
// range-fixup VALU ops (r18 regression), __expf adds a ln2-mul (pre-r18).
// Row max and sum are depth-5 trees. S^T = mfma(K,Q) so q = lane&31;
// P in registers via cvt_pk + permlane32_swap; O^T = mfma(V^T, P).
//   Kl[key][d]: byte = key*256 + ((2d) ^ ((key&15)<<4))   (reads 2-way, free)
//   Vl[d][k]:   byte = d*128  + ((2k) ^ ((d&7)<<4))       (reads 4-way, 1.58x)
__global__ __launch_bounds__(256, 2) void k_attn(const __bf16* __restrict__ qkv,
                                                 const __bf16* __restrict__ vt,
                                                 __bf16* __restrict__ o) {
  __shared__ __bf16 Kl[2][8192];
  __shared__ __bf16 Vl[2][8192];
  const int tid = threadIdx.x, lane = tid & 63, w = tid >> 6;
  const int l31 = lane & 31, h = lane >> 5;

  // block-id pairing: ids i and i+256 get tiles t and 15-t (uniform CU load)
  const int id = blockIdx.x;
  int tile, head;
  if (id < 256) { head = id >> 4; tile = id & 15; }
  else          { head = 16 + ((id - 256) >> 4); tile = 15 - (id & 15); }
  const int kvh = head >> 2;
  const int qbase = tile * 128 + w * 32;
  const int qg = qbase + l31;          // this lane's q row
  const int kdiag = (qbase + 31) >> 6; // last (partial) key tile for this wave
  const int nkt = 2 * tile + 2;

  // Q fragments (pre-scaled by log2e/sqrt(d) in QKV GEMM epilogue): B-frag col=q
  bf16x8 qf[8];
  {
    const __bf16* qrow = qkv + (size_t)qg * QKVN + head * HD;
#pragma unroll
    for (int dk = 0; dk < 8; dk++) qf[dk] = *(const bf16x8*)(qrow + dk * 16 + h * 8);
  }

  f32x16 acc[4];  // O^T: col=q=lane&31, row=d (reg-mapped), dt*32 block
#pragma unroll
  for (int dt = 0; dt < 4; dt++)
#pragma unroll
    for (int r = 0; r < 16; r++) acc[dt][r] = 0.f;
  float m = -INFINITY, lsum = 0.f;

#define STAGE(buf, ktile)                                                           \
  do {                                                                              \
    const int kk0 = (ktile) * 64;                                                   \
    _Pragma("unroll") for (int it = 0; it < 4; it++) {                              \
      int c = it * 256 + tid;                                                       \
      int key = c >> 4, slot = c & 15;                                              \
      int scol = ((slot * 16) ^ ((key & 15) << 4)) >> 1;                            \
      gload_lds16(qkv + (size_t)(kk0 + key) * QKVN + 4096 + kvh * HD + scol,        \
                  &Kl[buf][c * 8]);                                                 \
    }                                                                               \
    _Pragma("unroll") for (int it = 0; it < 4; it++) {                              \
      int c = it * 256 + tid;                                                       \
      int d = c >> 3, slot = c & 7;                                                 \
      int scol = ((slot * 16) ^ ((d & 7) << 4)) >> 1;                               \
      gload_lds16(vt + (size_t)(kvh * HD + d) * S_LEN + kk0 + scol,                 \
                  &Vl[buf][c * 8]);                                                 \
    }                                                                               \
  } while (0)

  STAGE(0, 0);
  __syncthreads();

  for (int kt = 0; kt < nkt; kt++) {
    const int cur = kt & 1;
    if (kt + 1 < nkt) STAGE(cur ^ 1, kt + 1);  // in flight during compute

    if (kt <= kdiag) {
      const char* Kb = (const char*)&Kl[cur][0];
      const char* Vb = (const char*)&Vl[cur][0];
      const int k0 = kt * 64;
      // ---- QK^T: S^T[key][q], two 32-key blocks ----
      f32x16 sacc[2];
#pragma unroll
      for (int b = 0; b < 2; b++)
#pragma unroll
        for (int r = 0; r < 16; r++) sacc[b][r] = 0.f;
      __builtin_amdgcn_s_setprio(1);
#pragma unroll
      for (int dk = 0; dk < 8; dk++) {
        const int sA = ((2 * dk + h) ^ (l31 & 15)) * 16;
        bf16x8 kf0 = *(const bf16x8*)(Kb + l31 * 256 + sA);
        bf16x8 kf1 = *(const bf16x8*)(Kb + (32 + l31) * 256 + sA);
        sacc[0] = mfma32(kf0, qf[dk], sacc[0]);
        sacc[1] = mfma32(kf1, qf[dk], sacc[1]);
      }
      __builtin_amdgcn_s_setprio(0);
      // ---- softmax in log2 domain (lane-local; q = lane&31) ----
      float p[32];
#pragma unroll
      for (int b = 0; b < 2; b++)
#pragma unroll
        for (int r = 0; r < 16; r++) p[b * 16 + r] = sacc[b][r];
      if (kt == kdiag) {  // mask only on the diagonal tile
#pragma unroll
        for (int b = 0; b < 2; b++)
#pragma unroll
          for (int r = 0; r < 16; r++) {
            int keyg = k0 + b * 32 + (r & 3) + 8 * (r >> 2) + 4 * h;
            if (keyg > qg) p[b * 16 + r] = -INFINITY;
          }
      }
      // pairwise max tree (depth 5)
      float t16[16], t8[8], t4[4];
#pragma unroll
      for (int i = 0; i < 16; i++) t16[i] = fmaxf(p[2 * i], p[2 * i + 1]);
#pragma unroll
      for (int i = 0; i < 8; i++) t8[i] = fmaxf(t16[2 * i], t16[2 * i + 1]);
#pragma unroll
      for (int i = 0; i < 4; i++) t4[i] = fmaxf(t8[2 * i], t8[2 * i + 1]);
      float pm = fmaxf(fmaxf(t4[0], t4[1]), fmaxf(t4[2], t4[3]));
      pm = fmaxf(pm, __shfl_xor(pm, 32));
      if (__any(pm - m > 8.f)) {  // defer-max (T13), log2 units
        float mn = fmaxf(m, pm);
        float corr = hw_exp2(m - mn);
        m = mn;
        lsum *= corr;
#pragma unroll
        for (int dt = 0; dt < 4; dt++)
#pragma unroll
          for (int r = 0; r < 16; r++) acc[dt][r] *= corr;
      }
      // p = 2^(s - m) via raw v_exp_f32; row-sum as depth-5 tree
#pragma unroll
      for (int i = 0; i < 32; i++) p[i] = hw_exp2(p[i] - m);
      float u16[16], u8[8], u4[4];
#pragma unroll
      for (int i = 0; i < 16; i++) u16[i] = p[2 * i] + p[2 * i + 1];
#pragma unroll
      for (int i = 0; i < 8; i++) u8[i] = u16[2 * i] + u16[2 * i + 1];
#pragma unroll
      for (int i = 0; i < 4; i++) u4[i] = u8[2 * i] + u8[2 * i + 1];
      lsum += (u4[0] + u4[1]) + (u4[2] + u4[3]);
      // ---- PV: O^T += V^T * P, P-frags built in-register ----
      // permlane32_swap(W0,W2): W0 -> {lo:W0@h0, hi:W2@h0}, W2 -> {lo:W0@h1, hi:W2@h1}.
#pragma unroll
      for (int ks2 = 0; ks2 < 4; ks2++) {
        const int o8 = (ks2 >> 1) * 16 + (ks2 & 1) * 8;
        u32 W0 = pk_bf16(p[o8 + 0], p[o8 + 1]);
        u32 W1 = pk_bf16(p[o8 + 2], p[o8 + 3]);
        u32 W2 = pk_bf16(p[o8 + 4], p[o8 + 5]);
        u32 W3 = pk_bf16(p[o8 + 6], p[o8 + 7]);
        asm("v_permlane32_swap_b32 %0, %1" : "+v"(W0), "+v"(W2));
        asm("v_permlane32_swap_b32 %0, %1" : "+v"(W1), "+v"(W3));
        union { u32 wd[4]; bf16x8 v; } pu;
        pu.wd[0] = W0; pu.wd[1] = W1; pu.wd[2] = W2; pu.wd[3] = W3;
        __builtin_amdgcn_s_setprio(1);
#pragma unroll
        for (int dt = 0; dt < 4; dt++) {
          const int dr = dt * 32 + l31;
          const int sV = ((2 * ks2 + h) ^ (dr & 7)) * 16;
          bf16x8 vf = *(const bf16x8*)(Vb + dr * 128 + sV);
          acc[dt] = mfma32(vf, pu.v, acc[dt]);
        }
        __builtin_amdgcn_s_setprio(0);
      }
    }
    __syncthreads();  // drains vmcnt: next tile landed; buffers safe to swap
  }
#undef STAGE

  // ---- finalize: combine the two key-halves, normalize, store ----
  lsum += __shfl_xor(lsum, 32);
  const float inv = 1.f / lsum;
  __bf16* orow = o + (size_t)qg * OD + head * HD;
#pragma unroll
  for (int dt = 0; dt < 4; dt++)
#pragma unroll
    for (int rq = 0; rq < 4; rq++) {  // reg quads -> 4 consecutive d
      int d = dt * 32 + 8 * rq + 4 * h;
      bf16x4 ov = {(__bf16)(acc[dt][rq * 4 + 0] * inv), (__bf16)(acc[dt][rq * 4 + 1] * inv),
                   (__bf16)(acc[dt][rq * 4 + 2] * inv), (__bf16)(acc[dt][rq * 4 + 3] * inv)};
      *(bf16x4*)(orow + d) = ov;
    }
}

extern "C" void kernel_launch(void* const* d_in, const int* in_sizes, int n_in,
                              void* d_out, int out_size, void* d_ws, size_t ws_size,
                              hipStream_t stream) {
  const float* x  = (const float*)d_in[0];
  // d_in[1] = mask (tril causal; hard-coded in kernel)
  const float* wq = (const float*)d_in[2];
  const float* bq = (const float*)d_in[3];
  const float* wk = (const float*)d_in[4];
  const float* bk = (const float*)d_in[5];
  const float* wv = (const float*)d_in[6];
  const float* bv = (const float*)d_in[7];
  const float* wo = (const float*)d_in[8];
  const float* bo = (const float*)d_in[9];
  float* out = (float*)d_out;

  const size_t MB = 1024 * 1024;
  char* ws = (char*)d_ws;
  __bf16* xb    = (__bf16*)(ws);             //  8 MiB: 2048x2048 (dead after QKV GEMM)
  __bf16* wqkvT = (__bf16*)(ws + 8 * MB);    // 24 MiB (dead after QKV GEMM)
  __bf16* woT   = (__bf16*)(ws + 32 * MB);   // 16 MiB: 2048x4096
  __bf16* qkvb  = (__bf16*)(ws + 48 * MB);   // 24 MiB: 2048x6144
  __bf16* vtb   = (__bf16*)(ws + 72 * MB);   //  4 MiB: 8x128x2048
  __bf16* ob    = (__bf16*)(ws + 76 * MB);   // 16 MiB: 2048x4096
  float*  bqkv  = (float*)(ws + 92 * MB);    // 24 KiB
  float*  Cpart = (float*)(ws);              // 32 MiB: 2x(2048x2048 f32), reuses xb+wqkvT

  k_cvt<<<4096, 256, 0, stream>>>(x, xb, HIDDEN * S_LEN);
  k_transpose_qkv<<<dim3(128, 64, 3), 256, 0, stream>>>(wq, wk, wv, wqkvT);
  k_transpose_cvt<<<dim3(64, 128), 256, 0, stream>>>(wo, woT, 4096, HIDDEN);
  k_bias_concat<<<24, 256, 0, stream>>>(bq, bk, bv, bqkv);

  // QKV projection: Q pre-scaled by log2(e)/sqrt(HD) so attention uses exp2
  k_gemm8<<<512, 256, 0, stream>>>(xb, wqkvT, bqkv, qkvb, S_LEN, QKVN, HIDDEN,
                                   0.12751743f, 4096);
  k_vtrans<<<dim3(S_LEN / 32, HD / 32, NKV), 256, 0, stream>>>(qkvb, vtb);
  k_attn<<<512, 256, 0, stream>>>(qkvb, vtb, ob);
  // O-projection: split-K=2, 2-phase counted-vmcnt dbuf (512 blocks = 2/CU)
  k_gemm_part<<<512, 256, 0, stream>>>(ob, woT, Cpart, S_LEN, HIDDEN, OD, OD / 2);
  k_ocombine<<<(S_LEN * HIDDEN) / 1024, 256, 0, stream>>>(
      Cpart, Cpart + (size_t)S_LEN * HIDDEN, bo, out);
}